// Round 4
// baseline (63.750 us; speedup 1.0000x reference)
//
#include <hip/hip_runtime.h>
#include <math.h>

// NEAT forward, round 4.
//  - f16 activations + f16 weights: inner loop is v_fma_mix_f32
//    (acc_f32 += f16_subword * f16_subword), no unpack instructions.
//  - prep kernel counting-sorts each neuron's 64 edges by LDS bank-pair
//    (idx & 15) and rotates by lane id, so at each gather wave-inst the 64
//    lanes' sorted positions cover 0..63 -> banks near-uniform (~4/bank,
//    the b64 minimum) instead of random (max ~8).
//  - records in d_ws: 16 B = {4x u16 idx, 4x f16 w}, layout
//    [group64][quad][lane] -> record load is one coalesced dwordx4/wave.

#define N_IN    512
#define NLAYER  9
#define DEG     64
#define BATCH   1024
#define BPB     4
#define THREADS 1024
#define TOTAL_N 8960            // 512 + 8*1024 + 256
#define N_OUT   256
#define NGROUP  132             // edge-owning neurons 8448 / 64
#define NREC    (NGROUP * 1024) // 135,168 records * 16 B = 2,162,688 B ws

union H4 { uint2 u; _Float16 h[4]; };
union H2 { unsigned u; _Float16 h[2]; };
union HS { _Float16 h; unsigned short s; };

// ---- prep: bank-sort + rotate edges, emit coalesced f16 records ----
__global__ __launch_bounds__(64)
void neat_prep(const float* __restrict__ wts,
               const int*   __restrict__ sidx,
               uint4*       __restrict__ rec)
{
    __shared__ int            sbin[64][16];
    __shared__ unsigned short srec[64 * 16 * 8];   // [neuron][quad][8 ushorts]

    const int t = threadIdx.x;
    const int g = blockIdx.x;                      // 64-neuron group
    const int layer = (g < 128) ? (g >> 4) : 8;
    const int nloc  = (g < 128) ? ((g & 15) << 6) + t : ((g - 128) << 6) + t;
    const int eoff  = (layer << 16) + (nloc << 6); // this neuron's 64 edges

    #pragma unroll
    for (int b = 0; b < 16; ++b) sbin[t][b] = 0;

    // pass 1: histogram of bank-pairs
    for (int e = 0; e < DEG; ++e) sbin[t][sidx[eoff + e] & 15]++;

    // exclusive prefix -> start cursors
    int run = 0;
    #pragma unroll
    for (int b = 0; b < 16; ++b) { int c = sbin[t][b]; sbin[t][b] = run; run += c; }

    // pass 2: place each edge at rotated record slot
    for (int e = 0; e < DEG; ++e) {
        const int idx = sidx[eoff + e];
        const int p   = sbin[t][idx & 15]++;       // sorted position
        const int slot = (p - t) & 63;             // slot s holds sorted[(s+t)&63]
        const int q = slot >> 2, gg = slot & 3;
        HS w; w.h = (_Float16)wts[eoff + e];
        srec[(t * 16 + q) * 8 + gg]     = (unsigned short)idx;
        srec[(t * 16 + q) * 8 + 4 + gg] = w.s;
    }
    __syncthreads();

    // coalesced copy out: rec[g*1024 + q*64 + lane]
    const uint4* sr = reinterpret_cast<const uint4*>(srec);
    for (int q = 0; q < 16; ++q)
        rec[(g << 10) + (q << 6) + t] = sr[t * 16 + q];
}

__global__ __launch_bounds__(THREADS, 4)
void neat_fwd(const float* __restrict__ in,
              const uint4* __restrict__ rec,
              float*       __restrict__ out)
{
    __shared__ _Float16 act[TOTAL_N * BPB];        // [neuron][batch], 71,680 B

    const int tid   = threadIdx.x;
    const int bbase = blockIdx.x * BPB;

    // ---- stage inputs (f32 -> f16) ----
    {
        const float* src = in + bbase * N_IN;
        for (int t = tid; t < BPB * N_IN; t += THREADS) {
            int j = t >> 9;           // batch sub
            int i = t & (N_IN - 1);   // input neuron
            act[i * BPB + j] = (_Float16)src[t];
        }
    }
    __syncthreads();

    int recBase = 0;
    int nb      = N_IN;
    #pragma unroll 1
    for (int layer = 0; layer < NLAYER; ++layer) {
        const int n = (layer < NLAYER - 1) ? 1024 : N_OUT;
        for (int neuron = tid; neuron < n; neuron += THREADS) {
            const uint4* rp = rec + recBase + ((neuron >> 6) << 10) + (neuron & 63);

            float4 acc = make_float4(0.f, 0.f, 0.f, 0.f);
            #pragma unroll 4
            for (int q = 0; q < DEG / 4; ++q) {
                const uint4 r4 = rp[q << 6];
                H4 g0, g1, g2, g3;
                g0.u = *reinterpret_cast<const uint2*>(act + ((r4.x & 0xffffu) << 2));
                g1.u = *reinterpret_cast<const uint2*>(act + ((r4.x >> 16) << 2));
                g2.u = *reinterpret_cast<const uint2*>(act + ((r4.y & 0xffffu) << 2));
                g3.u = *reinterpret_cast<const uint2*>(act + ((r4.y >> 16) << 2));
                H2 wz, ww; wz.u = r4.z; ww.u = r4.w;
                acc.x += (float)g0.h[0] * (float)wz.h[0];
                acc.y += (float)g0.h[1] * (float)wz.h[0];
                acc.z += (float)g0.h[2] * (float)wz.h[0];
                acc.w += (float)g0.h[3] * (float)wz.h[0];
                acc.x += (float)g1.h[0] * (float)wz.h[1];
                acc.y += (float)g1.h[1] * (float)wz.h[1];
                acc.z += (float)g1.h[2] * (float)wz.h[1];
                acc.w += (float)g1.h[3] * (float)wz.h[1];
                acc.x += (float)g2.h[0] * (float)ww.h[0];
                acc.y += (float)g2.h[1] * (float)ww.h[0];
                acc.z += (float)g2.h[2] * (float)ww.h[0];
                acc.w += (float)g2.h[3] * (float)ww.h[0];
                acc.x += (float)g3.h[0] * (float)ww.h[1];
                acc.y += (float)g3.h[1] * (float)ww.h[1];
                acc.z += (float)g3.h[2] * (float)ww.h[1];
                acc.w += (float)g3.h[3] * (float)ww.h[1];
            }

            float4 sg;
            sg.x = 1.f / (1.f + __expf(-acc.x));
            sg.y = 1.f / (1.f + __expf(-acc.y));
            sg.z = 1.f / (1.f + __expf(-acc.z));
            sg.w = 1.f / (1.f + __expf(-acc.w));

            if (layer < NLAYER - 1) {
                H4 p;
                p.h[0] = (_Float16)sg.x; p.h[1] = (_Float16)sg.y;
                p.h[2] = (_Float16)sg.z; p.h[3] = (_Float16)sg.w;
                *reinterpret_cast<uint2*>(act + ((nb + neuron) << 2)) = p.u;
            } else {
                float* op = out + neuron;           // f32 output, never quantized
                op[(bbase + 0) * N_OUT] = sg.x;
                op[(bbase + 1) * N_OUT] = sg.y;
                op[(bbase + 2) * N_OUT] = sg.z;
                op[(bbase + 3) * N_OUT] = sg.w;
            }
        }
        __syncthreads();
        recBase += n << 4;   // n * DEG / 4 records
        nb      += n;
    }
}

extern "C" void kernel_launch(void* const* d_in, const int* in_sizes, int n_in,
                              void* d_out, int out_size, void* d_ws, size_t ws_size,
                              hipStream_t stream)
{
    const float* in  = (const float*)d_in[0];
    const float* wts = (const float*)d_in[1];
    const int*   sx  = (const int*)d_in[2];
    float*       out = (float*)d_out;
    uint4*       rec = (uint4*)d_ws;    // 2,162,688 B

    neat_prep<<<NGROUP, 64, 0, stream>>>(wts, sx, rec);
    neat_fwd<<<BATCH / BPB, THREADS, 0, stream>>>(in, rec, out);
}

// Round 5
// 55.226 us; speedup vs baseline: 1.1543x; 1.1543x over previous
//
#include <hip/hip_runtime.h>
#include <math.h>

// NEAT forward, round 5.
//  - prep: bank-sort each neuron's 64 edges by LDS bank-pair (idx&15), then
//    assign sorted position (s + sigma(t)) & 63 to record slot s, with
//    sigma(t) = 4*(t&15) + (t>>4). At each gather wave-inst the 4 lanes
//    sharing (t&15) read consecutive sorted positions (one bank-pair =
//    4 words/bank, the b64 conflict-free floor) and the 16 (t&15) classes
//    cover all 16 bank-pairs. R4's sigma(t)=t put 4 lanes on the SAME
//    sorted run -> 8 words/bank; this fixes that.
//  - prep stages edges into padded LDS with coalesced loads (R4 prep was
//    stride-256B uncoalesced, sbin unpadded).
//  - fwd: neuron = tid; all 16 records prefetched into registers up front
//    (one L2 latency exposure per layer instead of 4).
//  - f16 act (8960*4*2 = 71,680 B LDS) + f16 weights, f32 accumulate,
//    final layer written f32 directly to out.

#define N_IN    512
#define NLAYER  9
#define DEG     64
#define BATCH   1024
#define BPB     4
#define THREADS 1024
#define TOTAL_N 8960            // 512 + 8*1024 + 256
#define N_OUT   256
#define NGROUP  132             // 8448 edge-owning neurons / 64

union H4 { uint2 u; _Float16 h[4]; };
union H2 { unsigned u; _Float16 h[2]; };
union HS { _Float16 h; unsigned short s; };

// ---- prep: bank-sort + class-strided rotation, coalesced f16 records ----
__global__ __launch_bounds__(64)
void neat_prep(const float* __restrict__ wts,
               const int*   __restrict__ sidx,
               uint4*       __restrict__ rec)
{
    __shared__ int            lidx[64 * 65];       // padded, 16,640 B
    __shared__ unsigned short lw  [64 * 65];       //          8,320 B
    __shared__ int            sbin[64 * 17];       // padded,  4,352 B
    __shared__ unsigned short srec[64 * 16 * 8];   //         16,384 B

    const int t     = threadIdx.x;
    const int g     = blockIdx.x;      // 64-neuron group; edges contiguous
    const int ebase = g << 12;         // g * 4096

    // coalesced staging: iter k loads neuron k's 64 edges (thread t = edge t)
    for (int k = 0; k < 64; ++k) {
        const int j = ebase + (k << 6) + t;
        lidx[k * 65 + t] = sidx[j];
        HS w; w.h = (_Float16)wts[j];
        lw[k * 65 + t] = w.s;
    }
    __syncthreads();

    // histogram of bank-pairs for neuron t
    #pragma unroll
    for (int b = 0; b < 16; ++b) sbin[t * 17 + b] = 0;
    for (int e = 0; e < DEG; ++e) sbin[t * 17 + (lidx[t * 65 + e] & 15)]++;

    // exclusive prefix -> cursors
    int run = 0;
    #pragma unroll
    for (int b = 0; b < 16; ++b) { int c = sbin[t*17+b]; sbin[t*17+b] = run; run += c; }

    // place: slot s holds sorted position (s + sigma(t)) & 63
    const int sigma = ((t & 15) << 2) | (t >> 4);
    for (int e = 0; e < DEG; ++e) {
        const int idx  = lidx[t * 65 + e];
        const int p    = sbin[t * 17 + (idx & 15)]++;   // sorted position
        const int slot = (p - sigma) & 63;
        const int q = slot >> 2, gg = slot & 3;
        srec[(t * 16 + q) * 8 + gg]     = (unsigned short)idx;
        srec[(t * 16 + q) * 8 + 4 + gg] = lw[t * 65 + e];
    }
    // srec written/read by same thread only -> no barrier needed

    const uint4* sr = reinterpret_cast<const uint4*>(srec);
    for (int q = 0; q < 16; ++q)
        rec[(g << 10) + (q << 6) + t] = sr[t * 16 + q];
}

__global__ __launch_bounds__(THREADS, 4)
void neat_fwd(const float* __restrict__ in,
              const uint4* __restrict__ rec,
              float*       __restrict__ out)
{
    __shared__ _Float16 act[TOTAL_N * BPB];        // [neuron][batch], 71,680 B

    const int tid   = threadIdx.x;
    const int bbase = blockIdx.x * BPB;

    // ---- stage inputs (f32 -> f16) ----
    {
        const float* src = in + bbase * N_IN;
        for (int t = tid; t < BPB * N_IN; t += THREADS) {
            int j = t >> 9;           // batch sub
            int i = t & (N_IN - 1);   // input neuron
            act[i * BPB + j] = (_Float16)src[t];
        }
    }
    __syncthreads();

    int recBase = 0;
    int nb      = N_IN;
    #pragma unroll 1
    for (int layer = 0; layer < NLAYER; ++layer) {
        const int n = (layer < NLAYER - 1) ? 1024 : N_OUT;
        if (tid < n) {
            const int neuron = tid;
            const uint4* rp = rec + recBase + ((neuron >> 6) << 10) + (neuron & 63);

            // prefetch all 16 records (static-indexed -> stays in VGPRs)
            uint4 r[16];
            #pragma unroll
            for (int q = 0; q < 16; ++q) r[q] = rp[q << 6];

            float4 acc = make_float4(0.f, 0.f, 0.f, 0.f);
            #pragma unroll
            for (int q = 0; q < 16; ++q) {
                const uint4 r4 = r[q];
                H4 g0, g1, g2, g3;
                g0.u = *reinterpret_cast<const uint2*>(act + ((r4.x & 0xffffu) << 2));
                g1.u = *reinterpret_cast<const uint2*>(act + ((r4.x >> 16) << 2));
                g2.u = *reinterpret_cast<const uint2*>(act + ((r4.y & 0xffffu) << 2));
                g3.u = *reinterpret_cast<const uint2*>(act + ((r4.y >> 16) << 2));
                H2 wz, ww; wz.u = r4.z; ww.u = r4.w;
                acc.x += (float)g0.h[0] * (float)wz.h[0];
                acc.y += (float)g0.h[1] * (float)wz.h[0];
                acc.z += (float)g0.h[2] * (float)wz.h[0];
                acc.w += (float)g0.h[3] * (float)wz.h[0];
                acc.x += (float)g1.h[0] * (float)wz.h[1];
                acc.y += (float)g1.h[1] * (float)wz.h[1];
                acc.z += (float)g1.h[2] * (float)wz.h[1];
                acc.w += (float)g1.h[3] * (float)wz.h[1];
                acc.x += (float)g2.h[0] * (float)ww.h[0];
                acc.y += (float)g2.h[1] * (float)ww.h[0];
                acc.z += (float)g2.h[2] * (float)ww.h[0];
                acc.w += (float)g2.h[3] * (float)ww.h[0];
                acc.x += (float)g3.h[0] * (float)ww.h[1];
                acc.y += (float)g3.h[1] * (float)ww.h[1];
                acc.z += (float)g3.h[2] * (float)ww.h[1];
                acc.w += (float)g3.h[3] * (float)ww.h[1];
            }

            float4 sg;
            sg.x = 1.f / (1.f + __expf(-acc.x));
            sg.y = 1.f / (1.f + __expf(-acc.y));
            sg.z = 1.f / (1.f + __expf(-acc.z));
            sg.w = 1.f / (1.f + __expf(-acc.w));

            if (layer < NLAYER - 1) {
                H4 p;
                p.h[0] = (_Float16)sg.x; p.h[1] = (_Float16)sg.y;
                p.h[2] = (_Float16)sg.z; p.h[3] = (_Float16)sg.w;
                *reinterpret_cast<uint2*>(act + ((nb + neuron) << 2)) = p.u;
            } else {
                float* op = out + neuron;           // f32 output, never quantized
                op[(bbase + 0) * N_OUT] = sg.x;
                op[(bbase + 1) * N_OUT] = sg.y;
                op[(bbase + 2) * N_OUT] = sg.z;
                op[(bbase + 3) * N_OUT] = sg.w;
            }
        }
        __syncthreads();
        recBase += n << 4;   // n * DEG / 4 records
        nb      += n;
    }
}

extern "C" void kernel_launch(void* const* d_in, const int* in_sizes, int n_in,
                              void* d_out, int out_size, void* d_ws, size_t ws_size,
                              hipStream_t stream)
{
    const float* in  = (const float*)d_in[0];
    const float* wts = (const float*)d_in[1];
    const int*   sx  = (const int*)d_in[2];
    float*       out = (float*)d_out;
    uint4*       rec = (uint4*)d_ws;    // 135,168 * 16 = 2,162,688 B

    neat_prep<<<NGROUP, 64, 0, stream>>>(wts, sx, rec);
    neat_fwd<<<BATCH / BPB, THREADS, 0, stream>>>(in, rec, out);
}